// Round 10
// baseline (118.282 us; speedup 1.0000x reference)
//
#include <hip/hip_runtime.h>
#include <math.h>

#define NN 8192
#define IN_F 128
#define OUT_F 64
#define KSL 32                  // K-slices (split-K)
#define BK 256                  // ints per K-slice
#define MC 256                  // rows per block
#define PSP 65                  // part row stride (f32)
#define LPP 264                 // Ps LDS pitch (bf16): 528B rows, 16B-aligned

typedef __bf16 bf16x8 __attribute__((ext_vector_type(8)));
typedef float f32x4 __attribute__((ext_vector_type(4)));
typedef unsigned long long u64;
typedef unsigned int u32;

// ---------------- K1: per node, Wh (64), s2 = lrelu(Wh).b[64:], E = exp(s2).
// Pt[f][row] = bf16(E*Wh_f), Pt[64][row] = bf16(E), rows 65..79 = 0.
__global__ __launch_bounds__(64) void k1_prep(const float* __restrict__ x,
                                              const float* __restrict__ W,
                                              const float* __restrict__ b,
                                              __bf16* __restrict__ Pt) {
    const int m0 = blockIdx.x * 4;
    const int f = threadIdx.x;
    const float4* x4 = (const float4*)(x + (size_t)m0 * IN_F);
    float wh0 = 0.f, wh1 = 0.f, wh2 = 0.f, wh3 = 0.f;
    #pragma unroll
    for (int k4 = 0; k4 < IN_F / 4; ++k4) {
        const float w0 = W[(k4 * 4 + 0) * OUT_F + f];
        const float w1 = W[(k4 * 4 + 1) * OUT_F + f];
        const float w2 = W[(k4 * 4 + 2) * OUT_F + f];
        const float w3 = W[(k4 * 4 + 3) * OUT_F + f];
        const float4 a0 = x4[k4];
        const float4 a1 = x4[32 + k4];
        const float4 a2 = x4[64 + k4];
        const float4 a3 = x4[96 + k4];
        wh0 = fmaf(a0.x, w0, fmaf(a0.y, w1, fmaf(a0.z, w2, fmaf(a0.w, w3, wh0))));
        wh1 = fmaf(a1.x, w0, fmaf(a1.y, w1, fmaf(a1.z, w2, fmaf(a1.w, w3, wh1))));
        wh2 = fmaf(a2.x, w0, fmaf(a2.y, w1, fmaf(a2.z, w2, fmaf(a2.w, w3, wh2))));
        wh3 = fmaf(a3.x, w0, fmaf(a3.y, w1, fmaf(a3.z, w2, fmaf(a3.w, w3, wh3))));
    }
    const float bb = b[OUT_F + f];
    float v0 = (wh0 >= 0.f ? wh0 : 0.2f * wh0) * bb;
    float v1 = (wh1 >= 0.f ? wh1 : 0.2f * wh1) * bb;
    float v2 = (wh2 >= 0.f ? wh2 : 0.2f * wh2) * bb;
    float v3 = (wh3 >= 0.f ? wh3 : 0.2f * wh3) * bb;
    #pragma unroll
    for (int off = 32; off; off >>= 1) {
        v0 += __shfl_xor(v0, off, 64);
        v1 += __shfl_xor(v1, off, 64);
        v2 += __shfl_xor(v2, off, 64);
        v3 += __shfl_xor(v3, off, 64);
    }
    const float E0 = expf(v0), E1 = expf(v1), E2 = expf(v2), E3 = expf(v3);
    Pt[(size_t)f * NN + m0 + 0] = (__bf16)(E0 * wh0);
    Pt[(size_t)f * NN + m0 + 1] = (__bf16)(E1 * wh1);
    Pt[(size_t)f * NN + m0 + 2] = (__bf16)(E2 * wh2);
    Pt[(size_t)f * NN + m0 + 3] = (__bf16)(E3 * wh3);
    if (f == 0) {
        Pt[(size_t)64 * NN + m0 + 0] = (__bf16)E0;
        Pt[(size_t)64 * NN + m0 + 1] = (__bf16)E1;
        Pt[(size_t)64 * NN + m0 + 2] = (__bf16)E2;
        Pt[(size_t)64 * NN + m0 + 3] = (__bf16)E3;
    }
    if (f < 60) {       // zero rows 65..79 for this block's 4 cols
        const int r = 65 + (f >> 2);
        const int c = f & 3;
        Pt[(size_t)r * NN + m0 + c] = (__bf16)0.f;
    }
}

// unpack byte (8 mask bits, k-ascending) -> bf16x8 of {0.0, 1.0}
__device__ __forceinline__ bf16x8 unp8b(u32 b) {
    union { u32 u[4]; bf16x8 h; } c;
    c.u[0] = ((b)      & 1u) * 0x3F80u | ((b >> 1) & 1u) * 0x3F800000u;
    c.u[1] = ((b >> 2) & 1u) * 0x3F80u | ((b >> 3) & 1u) * 0x3F800000u;
    c.u[2] = ((b >> 4) & 1u) * 0x3F80u | ((b >> 5) & 1u) * 0x3F800000u;
    c.u[3] = ((b >> 6) & 1u) * 0x3F80u | ((b >> 7) & 1u) * 0x3F800000u;
    return c.h;
}

// ---------------- K2 fused: stream adj once, ballot->regs, MFMA vs LDS-Ps.
// Block: 256 thr / 4 waves. Rows [mb, mb+256), K ints [k0, k0+256). No loop barriers.
__global__ __launch_bounds__(256, 2) void k2_fused(const int* __restrict__ adj,
                                                   const __bf16* __restrict__ Pt,
                                                   float* __restrict__ part) {
    const int bid = blockIdx.x;
    const int mb = (bid & 31) << 8;         // M-chunk base
    const int ksl = bid >> 5;               // K-slice
    const int k0 = ksl << 8;
    const int tid = threadIdx.x;
    const int w = tid >> 6, l = tid & 63;
    const int lm = l & 15, lg = l >> 4;

    __shared__ __bf16 Ps[80 * LPP];         // 42,240 B

    // stage Pt slice: 80 rows x 256 bf16; 2560 16B-chunks, 10/thread
    #pragma unroll
    for (int j = 0; j < 10; ++j) {
        const int c = tid + (j << 8);
        const int r = c >> 5, c16 = c & 31;
        *(uint4*)&Ps[r * LPP + (c16 << 3)] =
            *(const uint4*)(Pt + (size_t)r * NN + k0 + (c16 << 3));
    }
    __syncthreads();                        // the only barrier

    int4 L[16];
    const int lofs = l << 2;
    #define LD(itx)                                                          \
        {                                                                    \
            const int rb_ = mb + ((itx) << 6) + (w << 4);                    \
            _Pragma("unroll")                                                \
            for (int j = 0; j < 16; ++j)                                     \
                L[j] = *(const int4*)(adj + (size_t)(rb_ + j) * NN + k0 + lofs); \
        }

    LD(0)
    for (int it = 0; it < 4; ++it) {
        // marshal: ballots -> lane-private row bits (lane lm holds row rb+lm)
        u32 vA0 = 0, vA1 = 0, vA2 = 0, vA3 = 0, vA4 = 0, vA5 = 0, vA6 = 0, vA7 = 0;
        #pragma unroll
        for (int j = 0; j < 16; ++j) {
            const u64 b0 = __ballot(L[j].x != 0);
            const u64 b1 = __ballot(L[j].y != 0);
            const u64 b2 = __ballot(L[j].z != 0);
            const u64 b3 = __ballot(L[j].w != 0);
            if (lm == j) {
                vA0 = (u32)b0; vA1 = (u32)(b0 >> 32);
                vA2 = (u32)b1; vA3 = (u32)(b1 >> 32);
                vA4 = (u32)b2; vA5 = (u32)(b2 >> 32);
                vA6 = (u32)b3; vA7 = (u32)(b3 >> 32);
            }
        }
        if (it < 3) LD(it + 1)              // next-iter loads fly under MFMA

        f32x4 a0{}, a1{}, a2{}, a3{}, a4{};
        #pragma unroll
        for (int ks = 0; ks < 8; ++ks) {
            const u32 w0 = (ks < 4) ? vA0 : vA1;
            const u32 w1 = (ks < 4) ? vA2 : vA3;
            const u32 w2 = (ks < 4) ? vA4 : vA5;
            const u32 w3 = (ks < 4) ? vA6 : vA7;
            const int sh = ((ks & 3) << 3) + (lg << 1);
            const u32 t0 = (w0 >> sh) & 3u;
            const u32 t1 = (w1 >> sh) & 3u;
            const u32 t2 = (w2 >> sh) & 3u;
            const u32 t3 = (w3 >> sh) & 3u;
            const u32 byte = (t0 & 1u) | (t1 & 1u) << 1 | (t2 & 1u) << 2 |
                             (t3 & 1u) << 3 | (t0 & 2u) << 3 | (t1 & 2u) << 4 |
                             (t2 & 2u) << 5 | (t3 & 2u) << 6;
            const bf16x8 af = unp8b(byte);
            const int o = (ks << 5) + (lg << 3);
            const bf16x8 B0 = *(const bf16x8*)&Ps[(lm)      * LPP + o];
            const bf16x8 B1 = *(const bf16x8*)&Ps[(16 + lm) * LPP + o];
            const bf16x8 B2 = *(const bf16x8*)&Ps[(32 + lm) * LPP + o];
            const bf16x8 B3 = *(const bf16x8*)&Ps[(48 + lm) * LPP + o];
            const bf16x8 B4 = *(const bf16x8*)&Ps[(64 + lm) * LPP + o];
            a0 = __builtin_amdgcn_mfma_f32_16x16x32_bf16(af, B0, a0, 0, 0, 0);
            a1 = __builtin_amdgcn_mfma_f32_16x16x32_bf16(af, B1, a1, 0, 0, 0);
            a2 = __builtin_amdgcn_mfma_f32_16x16x32_bf16(af, B2, a2, 0, 0, 0);
            a3 = __builtin_amdgcn_mfma_f32_16x16x32_bf16(af, B3, a3, 0, 0, 0);
            a4 = __builtin_amdgcn_mfma_f32_16x16x32_bf16(af, B4, a4, 0, 0, 0);
        }

        // store: C/D col = lm, row = lg*4 + r within this iter's 16 rows
        float* pb = part + ((size_t)ksl * NN + mb + (it << 6) + (w << 4) + (lg << 2)) * PSP + lm;
        #pragma unroll
        for (int r = 0; r < 4; ++r) {
            pb[r * PSP]      = a0[r];
            pb[r * PSP + 16] = a1[r];
            pb[r * PSP + 32] = a2[r];
            pb[r * PSP + 48] = a3[r];
            if (lm == 0) pb[r * PSP + 64] = a4[r];
        }
    }
    #undef LD
}

// ---------------- K3: combine 32 splits, out = elu(num/den)
__global__ __launch_bounds__(256) void k3_combine(const float* __restrict__ part,
                                                  float* __restrict__ out) {
    const int idx = blockIdx.x * 256 + threadIdx.x;
    const int i = idx >> 6;
    const int f = idx & 63;
    float num = 0.f, den = 0.f;
    #pragma unroll
    for (int s = 0; s < KSL; ++s) {
        num += part[((size_t)s * NN + i) * PSP + f];
        den += part[((size_t)s * NN + i) * PSP + 64];
    }
    const float o = num / den;
    out[idx] = o > 0.f ? o : expm1f(o);
}

extern "C" void kernel_launch(void* const* d_in, const int* in_sizes, int n_in,
                              void* d_out, int out_size, void* d_ws, size_t ws_size,
                              hipStream_t stream) {
    const float* x   = (const float*)d_in[0];   // [8192,128]
    const int*   adj = (const int*)d_in[1];     // [8192,8192]
    const float* W   = (const float*)d_in[2];   // [128,64]
    const float* b   = (const float*)d_in[3];   // [128]
    float* out = (float*)d_out;

    __bf16* Pt  = (__bf16*)d_ws;                        // 80*8192*2 = 1.31 MB
    float* part = (float*)((char*)d_ws + (size_t)80 * NN * sizeof(__bf16));
                                                        // 32*8192*65*4 = 68.2 MB

    k1_prep<<<NN / 4, 64, 0, stream>>>(x, W, b, Pt);
    k2_fused<<<32 * KSL, 256, 0, stream>>>(adj, Pt, part);
    k3_combine<<<(NN * OUT_F) / 256, 256, 0, stream>>>(part, out);
}